// Round 7
// baseline (291.844 us; speedup 1.0000x reference)
//
#include <hip/hip_runtime.h>
#include <math.h>

// Problem constants
constexpr int C_ = 128, A_ = 64, K_ = 24, S_ = 4;
constexpr int NATOM = C_ * A_;    // 8192
constexpr int FAEV = 384;         // 64 radial + 320 angular
constexpr float RCR = 5.2f, RCA = 3.5f;
constexpr float PI_F = 3.14159265358979323846f;
// exp folded to exp2: exp(-eta*x^2) = exp2(K * x^2)
constexpr float K_A2 = -8.0f  * 1.44269504f;          // angular, on (hs - shfa)^2
constexpr float K_R2 = -64.0f * 1.44269504f;          // radial, on (d/2 - shfr/2)^2  (16*4)
constexpr float SQRT095 = 0.974679434f;               // sqrt(0.95) folded into unit vectors
constexpr float SQRT2   = 1.41421356237f;             // folded into fca (gives the 2* factor)

// transposed-weight region sizes (floats)
constexpr int W1N = S_ * FAEV * 160;   // 245760
constexpr int W2N = S_ * 160 * 128;    // 81920
constexpr int W3N = S_ * 128 * 96;     // 49152
constexpr int WTN = W1N + W2N + W3N;   // 376832

// ---------------- kernel A: AEV + species lists + out zero + weight transpose ----------------
// 4 atoms per block (one full wave per atom), grid = NATOM/4 = 2048
__global__ __launch_bounds__(256) void aev_kernel(const int* __restrict__ element_idxs,
                                                  const int* __restrict__ neighbor_idxs,
                                                  const float* __restrict__ distances,
                                                  const float* __restrict__ diff_vectors,
                                                  const float* __restrict__ W1,
                                                  const float* __restrict__ W2,
                                                  const float* __restrict__ W3,
                                                  float* __restrict__ aev_out,
                                                  int* __restrict__ mol_cnt,
                                                  int* __restrict__ mol_lst,
                                                  float* __restrict__ WT,
                                                  float* __restrict__ out) {
    const int blk = blockIdx.x;
    const int c   = blk >> 4;            // 16 blocks per molecule
    const int t   = threadIdx.x;

    // ---- side job: transpose weights into WT (W1T | W2T | W3T) ----
    {
        int gid = blk * 256 + t;
        if (gid < W1N) {
            int s = gid / (FAEV * 160), r = gid - s * (FAEV * 160);
            int f = r / 160, o = r - f * 160;
            WT[s * (FAEV * 160) + o * FAEV + f] = W1[gid];
        } else if (gid < W1N + W2N) {
            int g = gid - W1N;
            int s = g / (160 * 128), r = g - s * (160 * 128);
            int f = r / 128, o = r - f * 128;
            WT[W1N + s * (160 * 128) + o * 160 + f] = W2[g];
        } else if (gid < WTN) {
            int g = gid - W1N - W2N;
            int s = g / (128 * 96), r = g - s * (128 * 96);
            int f = r / 96, o = r - f * 96;
            WT[W1N + W2N + s * (128 * 96) + o * 128 + f] = W3[g];
        }
    }

    __shared__ int    elem_s[A_];
    __shared__ float4 u4_s[4][K_];       // {ux*s, uy*s, uz*s, d/2}  (s = sqrt(0.95)/d)
    __shared__ float  fcr_s[4][K_];
    __shared__ float  fca_s[4][K_];      // premultiplied by sqrt(2)
    __shared__ int    spec_s[4][K_];
    __shared__ int    bidx_s[4][S_][K_];
    __shared__ int    nsp_s[4][S_];

    if (t < A_) elem_s[t] = element_idxs[c * A_ + t];
    __syncthreads();

    // molecule-owner duties: build per-molecule species lists + zero out[c]
    if ((blk & 15) == 0) {
        if (t < S_) {
            int n = 0;
            int* lst = mol_lst + (c * S_ + t) * A_;
            for (int a = 0; a < A_; ++a)
                if (elem_s[a] == t) lst[n++] = a;
            mol_cnt[c * S_ + t] = n;
        } else if (t == S_) {
            out[c] = 0.0f;
        }
    }

    // load + precompute neighbor data (96 threads: 4 atoms x 24 nbrs)
    if (t < 4 * K_) {
        int m = t / K_, k = t - m * K_;
        int base = (blk * 4 + m) * K_ + k;
        int nb = neighbor_idxs[base];
        float d = distances[base];
        float inv = __builtin_amdgcn_rcpf(d) * SQRT095;
        float4 u;
        u.x = diff_vectors[base * 3 + 0] * inv;
        u.y = diff_vectors[base * 3 + 1] * inv;
        u.z = diff_vectors[base * 3 + 2] * inv;
        u.w = 0.5f * d;
        u4_s[m][k] = u;
        spec_s[m][k] = elem_s[nb];
        fcr_s[m][k] = (d < RCR) ? (0.5f * __cosf(PI_F * d * (1.0f / RCR)) + 0.5f) : 0.0f;
        fca_s[m][k] = (d < RCA) ? (SQRT2 * (0.5f * __cosf(PI_F * d * (1.0f / RCA)) + 0.5f)) : 0.0f;
    }
    __syncthreads();

    // bucket active neighbors by species (16 threads)
    if (t < 4 * S_) {
        int m = t >> 2, sp = t & 3, n = 0;
        #pragma unroll
        for (int k = 0; k < K_; ++k)
            if (fca_s[m][k] > 0.0f && spec_s[m][k] == sp) bidx_s[m][sp][n++] = k;
        nsp_s[m][sp] = n;
    }
    __syncthreads();

    // ---- per-atom phase: FULL wave per atom ----
    const int m      = t >> 6;           // 0..3
    const int lane   = t & 63;
    const int lane32 = lane & 31;
    const int par    = lane >> 5;        // pair-parity: low half = even pairs, high = odd
    float* aev = aev_out + (size_t)(blk * 4 + m) * FAEV;

    // radial: lane = sp*16 + shell  (64 features exactly)
    {
        const int   spg   = lane >> 4;
        const float shfrh = 0.5f * (0.9f + 0.26875f * (float)(lane & 15));
        float acc = 0.0f;
        #pragma unroll
        for (int k = 0; k < K_; ++k) {
            float hd = u4_s[m][k].w;
            float df = hd - shfrh;
            float term = 0.25f * exp2f(df * df * K_R2) * fcr_s[m][k];
            if (spec_s[m][k] == spg) acc += term;
        }
        aev[lane] = acc;
    }

    // angular: 10 species-pair segments; both wave halves = same atom, even/odd pairs
    const int zz = lane32 >> 2, yy = lane32 & 3;
    const float cz2 = 0.5f * __cosf(((float)zz + 0.5f) * (PI_F / 8.0f));
    const float sz2 = 0.5f * __sinf(((float)zz + 0.5f) * (PI_F / 8.0f));
    const float shfa_l = 0.9f + 0.65f * (float)yy;

    auto pair_term = [&](int j, int k2) -> float {
        float4 u1 = u4_s[m][j], u2 = u4_s[m][k2];
        float ca = u1.x * u2.x + u1.y * u2.y + u1.z * u2.z;   // = 0.95*cos
        float sa = sqrtf(1.0f - ca * ca);                     // ca^2 <= 0.9025, safe
        float dd = (u1.w + u2.w) - shfa_l;                    // (d1+d2)/2 - shfa
        float f2 = exp2f(dd * dd * K_A2);
        float x  = 0.5f + ca * cz2 + sa * sz2;
        float x2 = x * x, x4 = x2 * x2, x8 = x4 * x4, x16 = x8 * x8;
        float tc = fca_s[m][j] * fca_s[m][k2];                // = 2*fc1*fc2
        return (x16 * x16) * (f2 * tc);
    };

    #pragma unroll
    for (int spa = 0; spa < 4; ++spa) {
        #pragma unroll
        for (int spb = spa; spb < 4; ++spb) {
            const int pidx = spa * (9 - spa) / 2 + (spb - spa);
            const int na  = nsp_s[m][spa];
            const int nb2 = nsp_s[m][spb];
            float acc = 0.0f;
            if (spa == spb) {
                // triangular pair stream (jj<kk), stride 2 starting at parity
                int jj = 0, kk = 1 + par;
                while (jj < na - 1 && kk >= na) { int ov = kk - na; ++jj; kk = jj + 1 + ov; }
                while (jj < na - 1) {
                    acc += pair_term(bidx_s[m][spa][jj], bidx_s[m][spa][kk]);
                    kk += 2;
                    while (jj < na - 1 && kk >= na) { int ov = kk - na; ++jj; kk = jj + 1 + ov; }
                }
            } else {
                // rectangular pair stream
                int jj = 0, kk = par;
                while (jj < na && kk >= nb2) { kk -= nb2; ++jj; }
                while (jj < na) {
                    acc += pair_term(bidx_s[m][spa][jj], bidx_s[m][spb][kk]);
                    kk += 2;
                    while (jj < na && kk >= nb2) { kk -= nb2; ++jj; }
                }
            }
            float other = __shfl(acc, lane32 + 32);           // add the other half's partial
            if (lane < 32) aev[64 + pidx * 32 + lane32] = acc + other;
        }
    }
}

// ---------------- kernel B: MLP, 4 atoms of one (molecule, species) per block ----------------
// Transposed weights: per-thread float4 weight loads.
// Atom activations (layer 1): scalar loads straight from global aev_ws (wave-uniform rows).
__global__ __launch_bounds__(256) void mlp_kernel(const float* __restrict__ aev_ws,
                                                  const int* __restrict__ mol_cnt,
                                                  const int* __restrict__ mol_lst,
                                                  const float* __restrict__ WT,
                                                  const float* __restrict__ b1,
                                                  const float* __restrict__ b2,
                                                  const float* __restrict__ b3,
                                                  const float* __restrict__ W4,
                                                  const float* __restrict__ b4,
                                                  float* __restrict__ out) {
    const int blk   = blockIdx.x;
    const int cell  = blk / 6;           // 0..511 : (molecule, species)
    const int tile0 = blk - cell * 6;
    const int c     = cell >> 2;
    const int s     = cell & 3;
    const int cnt   = mol_cnt[c * S_ + s];
    const int t     = threadIdx.x;

    __shared__ __attribute__((aligned(16))) float h1_s[4][160];
    __shared__ __attribute__((aligned(16))) float h2_s[4][128];
    __shared__ __attribute__((aligned(16))) float h3_s[4][96];

    const float* W1T = WT + s * (FAEV * 160);
    const float* W2T = WT + W1N + s * (160 * 128);
    const float* W3T = WT + W1N + W2N + s * (128 * 96);
    const float* b1s = b1 + s * 160;
    const float* b2s = b2 + s * 128;
    const float* b3s = b3 + s * 96;
    const float* W4s = W4 + s * 96;
    const float  bb4 = b4[s];

    for (int tile = tile0; tile * 4 < cnt; tile += 6) {
        const int base   = tile * 4;
        const int matoms = min(4, cnt - base);

        // wave-uniform atom row pointers (scalar-load path)
        const float* row0;
        const float* row1;
        const float* row2;
        const float* row3;
        {
            int i0 = base + 0, i1 = min(base + 1, cnt - 1),
                i2 = min(base + 2, cnt - 1), i3 = min(base + 3, cnt - 1);
            const int* lst = mol_lst + (c * S_ + s) * A_;
            int a0 = __builtin_amdgcn_readfirstlane(lst[i0]);
            int a1 = __builtin_amdgcn_readfirstlane(lst[i1]);
            int a2 = __builtin_amdgcn_readfirstlane(lst[i2]);
            int a3 = __builtin_amdgcn_readfirstlane(lst[i3]);
            row0 = aev_ws + (size_t)(c * A_ + a0) * FAEV;
            row1 = aev_ws + (size_t)(c * A_ + a1) * FAEV;
            row2 = aev_ws + (size_t)(c * A_ + a2) * FAEV;
            row3 = aev_ws + (size_t)(c * A_ + a3) * FAEV;
        }

        // ---- layer 1: 384 -> 160 ----
        if (t < 160) {
            const float* w = W1T + t * FAEV;
            float acc0 = 0.f, acc1 = 0.f, acc2 = 0.f, acc3 = 0.f;
            #pragma unroll 8
            for (int f = 0; f < FAEV; f += 4) {
                float4 wv = *(const float4*)(w + f);
                float4 a0 = *(const float4*)(row0 + f);
                float4 a1 = *(const float4*)(row1 + f);
                float4 a2 = *(const float4*)(row2 + f);
                float4 a3 = *(const float4*)(row3 + f);
                acc0 += a0.x * wv.x + a0.y * wv.y + a0.z * wv.z + a0.w * wv.w;
                acc1 += a1.x * wv.x + a1.y * wv.y + a1.z * wv.z + a1.w * wv.w;
                acc2 += a2.x * wv.x + a2.y * wv.y + a2.z * wv.z + a2.w * wv.w;
                acc3 += a3.x * wv.x + a3.y * wv.y + a3.z * wv.z + a3.w * wv.w;
            }
            float bb = b1s[t];
            float x;
            x = acc0 + bb; h1_s[0][t] = (x > 0.f) ? x : 0.1f * (__expf(10.f * x) - 1.f);
            x = acc1 + bb; h1_s[1][t] = (x > 0.f) ? x : 0.1f * (__expf(10.f * x) - 1.f);
            x = acc2 + bb; h1_s[2][t] = (x > 0.f) ? x : 0.1f * (__expf(10.f * x) - 1.f);
            x = acc3 + bb; h1_s[3][t] = (x > 0.f) ? x : 0.1f * (__expf(10.f * x) - 1.f);
        }
        __syncthreads();

        // ---- layer 2: 160 -> 128 ----
        if (t < 128) {
            const float* w = W2T + t * 160;
            float acc0 = 0.f, acc1 = 0.f, acc2 = 0.f, acc3 = 0.f;
            #pragma unroll 8
            for (int f = 0; f < 160; f += 4) {
                float4 wv = *(const float4*)(w + f);
                float4 a0 = *(const float4*)&h1_s[0][f];
                float4 a1 = *(const float4*)&h1_s[1][f];
                float4 a2 = *(const float4*)&h1_s[2][f];
                float4 a3 = *(const float4*)&h1_s[3][f];
                acc0 += a0.x * wv.x + a0.y * wv.y + a0.z * wv.z + a0.w * wv.w;
                acc1 += a1.x * wv.x + a1.y * wv.y + a1.z * wv.z + a1.w * wv.w;
                acc2 += a2.x * wv.x + a2.y * wv.y + a2.z * wv.z + a2.w * wv.w;
                acc3 += a3.x * wv.x + a3.y * wv.y + a3.z * wv.z + a3.w * wv.w;
            }
            float bb = b2s[t];
            float x;
            x = acc0 + bb; h2_s[0][t] = (x > 0.f) ? x : 0.1f * (__expf(10.f * x) - 1.f);
            x = acc1 + bb; h2_s[1][t] = (x > 0.f) ? x : 0.1f * (__expf(10.f * x) - 1.f);
            x = acc2 + bb; h2_s[2][t] = (x > 0.f) ? x : 0.1f * (__expf(10.f * x) - 1.f);
            x = acc3 + bb; h2_s[3][t] = (x > 0.f) ? x : 0.1f * (__expf(10.f * x) - 1.f);
        }
        __syncthreads();

        // ---- layer 3: 128 -> 96 ----
        if (t < 96) {
            const float* w = W3T + t * 128;
            float acc0 = 0.f, acc1 = 0.f, acc2 = 0.f, acc3 = 0.f;
            #pragma unroll 8
            for (int f = 0; f < 128; f += 4) {
                float4 wv = *(const float4*)(w + f);
                float4 a0 = *(const float4*)&h2_s[0][f];
                float4 a1 = *(const float4*)&h2_s[1][f];
                float4 a2 = *(const float4*)&h2_s[2][f];
                float4 a3 = *(const float4*)&h2_s[3][f];
                acc0 += a0.x * wv.x + a0.y * wv.y + a0.z * wv.z + a0.w * wv.w;
                acc1 += a1.x * wv.x + a1.y * wv.y + a1.z * wv.z + a1.w * wv.w;
                acc2 += a2.x * wv.x + a2.y * wv.y + a2.z * wv.z + a2.w * wv.w;
                acc3 += a3.x * wv.x + a3.y * wv.y + a3.z * wv.z + a3.w * wv.w;
            }
            float bb = b3s[t];
            float x;
            x = acc0 + bb; h3_s[0][t] = (x > 0.f) ? x : 0.1f * (__expf(10.f * x) - 1.f);
            x = acc1 + bb; h3_s[1][t] = (x > 0.f) ? x : 0.1f * (__expf(10.f * x) - 1.f);
            x = acc2 + bb; h3_s[2][t] = (x > 0.f) ? x : 0.1f * (__expf(10.f * x) - 1.f);
            x = acc3 + bb; h3_s[3][t] = (x > 0.f) ? x : 0.1f * (__expf(10.f * x) - 1.f);
        }
        __syncthreads();

        // ---- layer 4: 96 -> 1, 32-lane parallel dot + shuffle reduce ----
        if (t < 128) {
            int m = t >> 5, l = t & 31;
            if (m < matoms) {
                float p = h3_s[m][l]      * W4s[l]
                        + h3_s[m][l + 32] * W4s[l + 32]
                        + h3_s[m][l + 64] * W4s[l + 64];
                #pragma unroll
                for (int off = 16; off >= 1; off >>= 1)
                    p += __shfl_xor(p, off, 32);
                if (l == 0) atomicAdd(&out[c], p + bb4);
            }
        }
        __syncthreads();   // protect LDS before next tile (rare second iteration)
    }
}

extern "C" void kernel_launch(void* const* d_in, const int* in_sizes, int n_in,
                              void* d_out, int out_size, void* d_ws, size_t ws_size,
                              hipStream_t stream) {
    const int*   element_idxs  = (const int*)d_in[0];
    const int*   neighbor_idxs = (const int*)d_in[1];
    const float* distances     = (const float*)d_in[2];
    const float* diff_vectors  = (const float*)d_in[3];
    const float* W1 = (const float*)d_in[4];
    const float* b1 = (const float*)d_in[5];
    const float* W2 = (const float*)d_in[6];
    const float* b2 = (const float*)d_in[7];
    const float* W3 = (const float*)d_in[8];
    const float* b3 = (const float*)d_in[9];
    const float* W4 = (const float*)d_in[10];
    const float* b4 = (const float*)d_in[11];
    float* out = (float*)d_out;

    // workspace layout
    float* aev_ws  = (float*)d_ws;                                       // 8192*384 f32 = 12.58 MB
    int*   mol_cnt = (int*)((char*)d_ws + (size_t)NATOM * FAEV * 4);     // 512 ints
    int*   mol_lst = mol_cnt + C_ * S_;                                  // 512*64 ints
    float* WT      = (float*)(mol_lst + C_ * S_ * A_);                   // 376832 f32 = 1.5 MB

    hipLaunchKernelGGL(aev_kernel, dim3(NATOM / 4), dim3(256), 0, stream,
                       element_idxs, neighbor_idxs, distances, diff_vectors,
                       W1, W2, W3, aev_ws, mol_cnt, mol_lst, WT, out);
    hipLaunchKernelGGL(mlp_kernel, dim3(C_ * S_ * 6), dim3(256), 0, stream,
                       aev_ws, mol_cnt, mol_lst, WT, b1, b2, b3, W4, b4, out);
}

// Round 8
// 274.255 us; speedup vs baseline: 1.0641x; 1.0641x over previous
//
#include <hip/hip_runtime.h>
#include <math.h>

// Problem constants
constexpr int C_ = 128, A_ = 64, K_ = 24, S_ = 4;
constexpr int NATOM = C_ * A_;    // 8192
constexpr int FAEV = 384;         // 64 radial + 320 angular
constexpr float RCR = 5.2f, RCA = 3.5f;
constexpr float PI_F = 3.14159265358979323846f;
// exp folded to exp2: exp(-eta*x^2) = exp2(K * x^2)
constexpr float K_A2 = -8.0f  * 1.44269504f;          // angular, on (hs - shfa)^2
constexpr float K_R2 = -64.0f * 1.44269504f;          // radial, on (d/2 - shfr/2)^2  (16*4)
constexpr float SQRT095 = 0.974679434f;               // sqrt(0.95) folded into unit vectors
constexpr float SQRT2   = 1.41421356237f;             // folded into fca (gives the 2* factor)

constexpr int MLP_TILES = 288;    // tiles of 8 atoms per species (stride loop covers overflow)

// ---------------- kernel A: AEV + per-molecule species lists + out zero ----------------
// 4 atoms per block (one full wave per atom), grid = NATOM/4 = 2048
__global__ __launch_bounds__(256) void aev_kernel(const int* __restrict__ element_idxs,
                                                  const int* __restrict__ neighbor_idxs,
                                                  const float* __restrict__ distances,
                                                  const float* __restrict__ diff_vectors,
                                                  float* __restrict__ aev_out,
                                                  int* __restrict__ mol_cnt,
                                                  int* __restrict__ mol_lst,
                                                  float* __restrict__ out) {
    const int blk = blockIdx.x;
    const int c   = blk >> 4;            // 16 blocks per molecule
    const int t   = threadIdx.x;

    __shared__ int    elem_s[A_];
    __shared__ float4 u4_s[4][K_];       // {ux*s, uy*s, uz*s, d/2}  (s = sqrt(0.95)/d)
    __shared__ float  fcr_s[4][K_];
    __shared__ float  fca_s[4][K_];      // premultiplied by sqrt(2)
    __shared__ int    spec_s[4][K_];
    __shared__ int    bidx_s[4][S_][K_];
    __shared__ int    nsp_s[4][S_];

    if (t < A_) elem_s[t] = element_idxs[c * A_ + t];
    __syncthreads();

    // molecule-owner duties: build per-molecule species lists + zero out[c]
    if ((blk & 15) == 0) {
        if (t < S_) {
            int n = 0;
            int* lst = mol_lst + (c * S_ + t) * A_;
            for (int a = 0; a < A_; ++a)
                if (elem_s[a] == t) lst[n++] = a;
            mol_cnt[c * S_ + t] = n;
        } else if (t == S_) {
            out[c] = 0.0f;
        }
    }

    // load + precompute neighbor data (96 threads: 4 atoms x 24 nbrs)
    if (t < 4 * K_) {
        int m = t / K_, k = t - m * K_;
        int base = (blk * 4 + m) * K_ + k;
        int nb = neighbor_idxs[base];
        float d = distances[base];
        float inv = __builtin_amdgcn_rcpf(d) * SQRT095;
        float4 u;
        u.x = diff_vectors[base * 3 + 0] * inv;
        u.y = diff_vectors[base * 3 + 1] * inv;
        u.z = diff_vectors[base * 3 + 2] * inv;
        u.w = 0.5f * d;
        u4_s[m][k] = u;
        spec_s[m][k] = elem_s[nb];
        fcr_s[m][k] = (d < RCR) ? (0.5f * __cosf(PI_F * d * (1.0f / RCR)) + 0.5f) : 0.0f;
        fca_s[m][k] = (d < RCA) ? (SQRT2 * (0.5f * __cosf(PI_F * d * (1.0f / RCA)) + 0.5f)) : 0.0f;
    }
    __syncthreads();

    // bucket active neighbors by species (16 threads)
    if (t < 4 * S_) {
        int m = t >> 2, sp = t & 3, n = 0;
        #pragma unroll
        for (int k = 0; k < K_; ++k)
            if (fca_s[m][k] > 0.0f && spec_s[m][k] == sp) bidx_s[m][sp][n++] = k;
        nsp_s[m][sp] = n;
    }
    __syncthreads();

    // ---- per-atom phase: FULL wave per atom ----
    const int m      = t >> 6;           // 0..3
    const int lane   = t & 63;
    const int lane32 = lane & 31;
    const int par    = lane >> 5;        // pair-parity: low half = even pairs, high = odd
    float* aev = aev_out + (size_t)(blk * 4 + m) * FAEV;

    // radial: lane = sp*16 + shell  (64 features exactly)
    {
        const int   spg   = lane >> 4;
        const float shfrh = 0.5f * (0.9f + 0.26875f * (float)(lane & 15));
        float acc = 0.0f;
        #pragma unroll
        for (int k = 0; k < K_; ++k) {
            float hd = u4_s[m][k].w;
            float df = hd - shfrh;
            float term = 0.25f * exp2f(df * df * K_R2) * fcr_s[m][k];
            if (spec_s[m][k] == spg) acc += term;
        }
        aev[lane] = acc;
    }

    // angular: 10 species-pair segments; both wave halves = same atom, even/odd pairs
    const int zz = lane32 >> 2, yy = lane32 & 3;
    const float cz2 = 0.5f * __cosf(((float)zz + 0.5f) * (PI_F / 8.0f));
    const float sz2 = 0.5f * __sinf(((float)zz + 0.5f) * (PI_F / 8.0f));
    const float shfa_l = 0.9f + 0.65f * (float)yy;

    auto pair_term = [&](int j, int k2) -> float {
        float4 u1 = u4_s[m][j], u2 = u4_s[m][k2];
        float ca = u1.x * u2.x + u1.y * u2.y + u1.z * u2.z;   // = 0.95*cos
        float sa = sqrtf(1.0f - ca * ca);                     // ca^2 <= 0.9025, safe
        float dd = (u1.w + u2.w) - shfa_l;                    // (d1+d2)/2 - shfa
        float f2 = exp2f(dd * dd * K_A2);
        float x  = 0.5f + ca * cz2 + sa * sz2;
        float x2 = x * x, x4 = x2 * x2, x8 = x4 * x4, x16 = x8 * x8;
        float tc = fca_s[m][j] * fca_s[m][k2];                // = 2*fc1*fc2
        return (x16 * x16) * (f2 * tc);
    };

    #pragma unroll
    for (int spa = 0; spa < 4; ++spa) {
        #pragma unroll
        for (int spb = spa; spb < 4; ++spb) {
            const int pidx = spa * (9 - spa) / 2 + (spb - spa);
            const int na  = nsp_s[m][spa];
            const int nb2 = nsp_s[m][spb];
            float acc = 0.0f;
            if (spa == spb) {
                // triangular pair stream (jj<kk), stride 2 starting at parity
                int jj = 0, kk = 1 + par;
                while (jj < na - 1 && kk >= na) { int ov = kk - na; ++jj; kk = jj + 1 + ov; }
                while (jj < na - 1) {
                    acc += pair_term(bidx_s[m][spa][jj], bidx_s[m][spa][kk]);
                    kk += 2;
                    while (jj < na - 1 && kk >= na) { int ov = kk - na; ++jj; kk = jj + 1 + ov; }
                }
            } else {
                // rectangular pair stream
                int jj = 0, kk = par;
                while (jj < na && kk >= nb2) { kk -= nb2; ++jj; }
                while (jj < na) {
                    acc += pair_term(bidx_s[m][spa][jj], bidx_s[m][spb][kk]);
                    kk += 2;
                    while (jj < na && kk >= nb2) { kk -= nb2; ++jj; }
                }
            }
            float other = __shfl(acc, lane32 + 32);           // add the other half's partial
            if (lane < 32) aev[64 + pidx * 32 + lane32] = acc + other;
        }
    }
}

// ---------------- kernel B: MLP, 8 atoms of one species (global tile) per block ----------------
// Global species-list index reconstructed via a 64-lane shuffle prefix scan over mol_cnt
// (no atomics, no extra launch). Coalesced W[f][o] weight loads; 8-atom acc registers.
__global__ __launch_bounds__(256) void mlp_kernel(const float* __restrict__ aev_ws,
                                                  const int* __restrict__ mol_cnt,
                                                  const int* __restrict__ mol_lst,
                                                  const float* __restrict__ W1, const float* __restrict__ b1,
                                                  const float* __restrict__ W2, const float* __restrict__ b2,
                                                  const float* __restrict__ W3, const float* __restrict__ b3,
                                                  const float* __restrict__ W4, const float* __restrict__ b4,
                                                  float* __restrict__ out) {
    const int blk   = blockIdx.x;
    const int s     = blk & 3;
    const int tile0 = blk >> 2;
    const int t     = threadIdx.x;
    const int lane  = t & 63;

    // ---- 64-lane prefix scan over per-molecule species counts ----
    const int c0 = lane * 2, c1 = c0 + 1;
    const int n0 = mol_cnt[c0 * S_ + s];
    const int n1 = mol_cnt[c1 * S_ + s];
    const int pairc = n0 + n1;
    int scan = pairc;                     // inclusive scan over lane pairs
    #pragma unroll
    for (int off = 1; off < 64; off <<= 1) {
        int v = __shfl_up(scan, off);
        if (lane >= off) scan += v;
    }
    const int cntS = __shfl(scan, 63);

    __shared__ __attribute__((aligned(16))) float aev_s[8][FAEV];  // overlays h2(8x128)+h3(8x96)
    __shared__ __attribute__((aligned(16))) float h1_s[8][160];
    float (*h2_s)[128] = (float(*)[128])&aev_s[0][0];
    float (*h3_s)[96]  = (float(*)[96])(&aev_s[0][0] + 8 * 128);

    const float* W1s = W1 + s * (FAEV * 160);
    const float* b1s = b1 + s * 160;
    const float* W2s = W2 + s * (160 * 128);
    const float* b2s = b2 + s * 128;
    const float* W3s = W3 + s * (128 * 96);
    const float* b3s = b3 + s * 96;
    const float* W4s = W4 + s * 96;
    const float  bb4 = b4[s];

    for (int tile = tile0; tile * 8 < cntS; tile += MLP_TILES) {
        const int base = tile * 8;

        // ---- resolve the 8 global-list slots to absolute atom ids (all waves, no LDS) ----
        int myAtom = -1;                  // absolute atom id for this thread's row m = t>>5
        #pragma unroll
        for (int m = 0; m < 8; ++m) {
            int g = base + m;
            int atomAbs = -1;
            if (g < cntS) {
                unsigned long long mask = __ballot(scan > g);
                int L = (int)__builtin_ctzll(mask);
                int exclL = __shfl(scan, L) - __shfl(pairc, L);
                int n0L   = __shfl(n0, L);
                int loc = g - exclL;
                int cL  = 2 * L;
                if (loc >= n0L) { cL += 1; loc -= n0L; }
                atomAbs = cL * A_ + mol_lst[(cL * S_ + s) * A_ + loc];
            }
            if ((t >> 5) == m) myAtom = atomAbs;
        }

        // ---- load 8 AEV rows (32 lanes per row, 3 float4 each) ----
        {
            int mrow = t >> 5, l = t & 31;
            float4* dst = (float4*)&aev_s[mrow][0];
            if (myAtom >= 0) {
                const float4* src = (const float4*)(aev_ws + (size_t)myAtom * FAEV);
                dst[l]      = src[l];
                dst[l + 32] = src[l + 32];
                dst[l + 64] = src[l + 64];
            } else {
                dst[l]      = make_float4(0.f, 0.f, 0.f, 0.f);
                dst[l + 32] = make_float4(0.f, 0.f, 0.f, 0.f);
                dst[l + 64] = make_float4(0.f, 0.f, 0.f, 0.f);
            }
        }
        __syncthreads();

        // ---- layer 1: 384 -> 160 ----
        if (t < 160) {
            float acc[8];
            #pragma unroll
            for (int m = 0; m < 8; ++m) acc[m] = 0.0f;
            #pragma unroll 4
            for (int f = 0; f < FAEV; f += 4) {
                float w0 = W1s[(f + 0) * 160 + t];
                float w1 = W1s[(f + 1) * 160 + t];
                float w2 = W1s[(f + 2) * 160 + t];
                float w3 = W1s[(f + 3) * 160 + t];
                #pragma unroll
                for (int m = 0; m < 8; ++m) {
                    float4 av = *(const float4*)&aev_s[m][f];   // LDS broadcast
                    acc[m] += av.x * w0 + av.y * w1 + av.z * w2 + av.w * w3;
                }
            }
            float bb = b1s[t];
            #pragma unroll
            for (int m = 0; m < 8; ++m) {
                float x = acc[m] + bb;
                h1_s[m][t] = (x > 0.f) ? x : 0.1f * (__expf(10.f * x) - 1.f);
            }
        }
        __syncthreads();   // aev_s dead -> reuse as h2/h3

        // ---- layer 2: 160 -> 128 ----
        if (t < 128) {
            float acc[8];
            #pragma unroll
            for (int m = 0; m < 8; ++m) acc[m] = 0.0f;
            #pragma unroll 4
            for (int f = 0; f < 160; f += 4) {
                float w0 = W2s[(f + 0) * 128 + t];
                float w1 = W2s[(f + 1) * 128 + t];
                float w2 = W2s[(f + 2) * 128 + t];
                float w3 = W2s[(f + 3) * 128 + t];
                #pragma unroll
                for (int m = 0; m < 8; ++m) {
                    float4 av = *(const float4*)&h1_s[m][f];
                    acc[m] += av.x * w0 + av.y * w1 + av.z * w2 + av.w * w3;
                }
            }
            float bb = b2s[t];
            #pragma unroll
            for (int m = 0; m < 8; ++m) {
                float x = acc[m] + bb;
                h2_s[m][t] = (x > 0.f) ? x : 0.1f * (__expf(10.f * x) - 1.f);
            }
        }
        __syncthreads();

        // ---- layer 3: 128 -> 96 ----
        if (t < 96) {
            float acc[8];
            #pragma unroll
            for (int m = 0; m < 8; ++m) acc[m] = 0.0f;
            #pragma unroll 4
            for (int f = 0; f < 128; f += 4) {
                float w0 = W3s[(f + 0) * 96 + t];
                float w1 = W3s[(f + 1) * 96 + t];
                float w2 = W3s[(f + 2) * 96 + t];
                float w3 = W3s[(f + 3) * 96 + t];
                #pragma unroll
                for (int m = 0; m < 8; ++m) {
                    float4 av = *(const float4*)&h2_s[m][f];
                    acc[m] += av.x * w0 + av.y * w1 + av.z * w2 + av.w * w3;
                }
            }
            float bb = b3s[t];
            #pragma unroll
            for (int m = 0; m < 8; ++m) {
                float x = acc[m] + bb;
                h3_s[m][t] = (x > 0.f) ? x : 0.1f * (__expf(10.f * x) - 1.f);
            }
        }
        __syncthreads();

        // ---- layer 4: 96 -> 1, all 8 rows in parallel (32 lanes each) ----
        {
            int m = t >> 5, l = t & 31;
            if (myAtom >= 0) {
                float p = h3_s[m][l]      * W4s[l]
                        + h3_s[m][l + 32] * W4s[l + 32]
                        + h3_s[m][l + 64] * W4s[l + 64];
                #pragma unroll
                for (int off = 16; off >= 1; off >>= 1)
                    p += __shfl_xor(p, off, 32);
                if (l == 0) atomicAdd(&out[myAtom >> 6], p + bb4);
            }
        }
        __syncthreads();   // protect LDS before next tile (rare stride iteration)
    }
}

extern "C" void kernel_launch(void* const* d_in, const int* in_sizes, int n_in,
                              void* d_out, int out_size, void* d_ws, size_t ws_size,
                              hipStream_t stream) {
    const int*   element_idxs  = (const int*)d_in[0];
    const int*   neighbor_idxs = (const int*)d_in[1];
    const float* distances     = (const float*)d_in[2];
    const float* diff_vectors  = (const float*)d_in[3];
    const float* W1 = (const float*)d_in[4];
    const float* b1 = (const float*)d_in[5];
    const float* W2 = (const float*)d_in[6];
    const float* b2 = (const float*)d_in[7];
    const float* W3 = (const float*)d_in[8];
    const float* b3 = (const float*)d_in[9];
    const float* W4 = (const float*)d_in[10];
    const float* b4 = (const float*)d_in[11];
    float* out = (float*)d_out;

    // workspace layout
    float* aev_ws  = (float*)d_ws;                                       // 8192*384 f32 = 12.58 MB
    int*   mol_cnt = (int*)((char*)d_ws + (size_t)NATOM * FAEV * 4);     // 512 ints
    int*   mol_lst = mol_cnt + C_ * S_;                                  // 512*64 ints

    hipLaunchKernelGGL(aev_kernel, dim3(NATOM / 4), dim3(256), 0, stream,
                       element_idxs, neighbor_idxs, distances, diff_vectors,
                       aev_ws, mol_cnt, mol_lst, out);
    hipLaunchKernelGGL(mlp_kernel, dim3(S_ * MLP_TILES), dim3(256), 0, stream,
                       aev_ws, mol_cnt, mol_lst,
                       W1, b1, W2, b2, W3, b3, W4, b4, out);
}

// Round 9
// 251.746 us; speedup vs baseline: 1.1593x; 1.0894x over previous
//
#include <hip/hip_runtime.h>
#include <math.h>

// Problem constants
constexpr int C_ = 128, A_ = 64, K_ = 24, S_ = 4;
constexpr int NATOM = C_ * A_;    // 8192
constexpr int FAEV = 384;         // 64 radial + 320 angular
constexpr float RCR = 5.2f, RCA = 3.5f;
constexpr float PI_F = 3.14159265358979323846f;
// exp folded to exp2: exp(-eta*x^2) = exp2(K * x^2)
constexpr float K_A2 = -8.0f  * 1.44269504f;          // angular, on (hs - shfa)^2
constexpr float K_R2 = -64.0f * 1.44269504f;          // radial, on (d/2 - shfr/2)^2  (16*4)
constexpr float SQRT095 = 0.974679434f;               // sqrt(0.95) folded into unit vectors
constexpr float SQRT2   = 1.41421356237f;             // folded into fca (gives the 2* factor)

constexpr int MLP_TILES = 288;    // tiles of 8 atoms per species (stride loop covers overflow)

// ---------------- kernel A: AEV + per-molecule species lists + out zero ----------------
// 4 atoms per block (one full wave per atom), grid = NATOM/4 = 2048
__global__ __launch_bounds__(256) void aev_kernel(const int* __restrict__ element_idxs,
                                                  const int* __restrict__ neighbor_idxs,
                                                  const float* __restrict__ distances,
                                                  const float* __restrict__ diff_vectors,
                                                  float* __restrict__ aev_out,
                                                  int* __restrict__ mol_cnt,
                                                  int* __restrict__ mol_lst,
                                                  float* __restrict__ out) {
    const int blk = blockIdx.x;
    const int c   = blk >> 4;            // 16 blocks per molecule
    const int t   = threadIdx.x;

    __shared__ int    elem_s[A_];
    __shared__ float4 u4_s[4][K_];       // {ux*s, uy*s, uz*s, d/2}  (s = sqrt(0.95)/d)
    __shared__ float  fcr_s[4][K_];
    __shared__ float  fca_s[4][K_];      // premultiplied by sqrt(2)
    __shared__ int    spec_s[4][K_];
    __shared__ int    bidx_s[4][S_][K_];
    __shared__ int    nsp_s[4][S_];

    if (t < A_) elem_s[t] = element_idxs[c * A_ + t];
    __syncthreads();

    // molecule-owner duties: build per-molecule species lists + zero out[c]
    if ((blk & 15) == 0) {
        if (t < S_) {
            int n = 0;
            int* lst = mol_lst + (c * S_ + t) * A_;
            for (int a = 0; a < A_; ++a)
                if (elem_s[a] == t) lst[n++] = a;
            mol_cnt[c * S_ + t] = n;
        } else if (t == S_) {
            out[c] = 0.0f;
        }
    }

    // load + precompute neighbor data (96 threads: 4 atoms x 24 nbrs)
    if (t < 4 * K_) {
        int m = t / K_, k = t - m * K_;
        int base = (blk * 4 + m) * K_ + k;
        int nb = neighbor_idxs[base];
        float d = distances[base];
        float inv = __builtin_amdgcn_rcpf(d) * SQRT095;
        float4 u;
        u.x = diff_vectors[base * 3 + 0] * inv;
        u.y = diff_vectors[base * 3 + 1] * inv;
        u.z = diff_vectors[base * 3 + 2] * inv;
        u.w = 0.5f * d;
        u4_s[m][k] = u;
        spec_s[m][k] = elem_s[nb];
        fcr_s[m][k] = (d < RCR) ? (0.5f * __cosf(PI_F * d * (1.0f / RCR)) + 0.5f) : 0.0f;
        fca_s[m][k] = (d < RCA) ? (SQRT2 * (0.5f * __cosf(PI_F * d * (1.0f / RCA)) + 0.5f)) : 0.0f;
    }
    __syncthreads();

    // bucket active neighbors by species (16 threads)
    if (t < 4 * S_) {
        int m = t >> 2, sp = t & 3, n = 0;
        #pragma unroll
        for (int k = 0; k < K_; ++k)
            if (fca_s[m][k] > 0.0f && spec_s[m][k] == sp) bidx_s[m][sp][n++] = k;
        nsp_s[m][sp] = n;
    }
    __syncthreads();

    // ---- per-atom phase: FULL wave per atom ----
    const int m      = t >> 6;           // 0..3
    const int lane   = t & 63;
    const int lane32 = lane & 31;
    const int par    = lane >> 5;        // pair-parity: low half = even pairs, high = odd
    float* aev = aev_out + (size_t)(blk * 4 + m) * FAEV;

    // radial: lane = sp*16 + shell  (64 features exactly)
    {
        const int   spg   = lane >> 4;
        const float shfrh = 0.5f * (0.9f + 0.26875f * (float)(lane & 15));
        float acc = 0.0f;
        #pragma unroll
        for (int k = 0; k < K_; ++k) {
            float hd = u4_s[m][k].w;
            float df = hd - shfrh;
            float term = 0.25f * exp2f(df * df * K_R2) * fcr_s[m][k];
            if (spec_s[m][k] == spg) acc += term;
        }
        aev[lane] = acc;
    }

    // angular: 10 species-pair segments; both wave halves = same atom, even/odd pairs
    const int zz = lane32 >> 2, yy = lane32 & 3;
    const float cz2 = 0.5f * __cosf(((float)zz + 0.5f) * (PI_F / 8.0f));
    const float sz2 = 0.5f * __sinf(((float)zz + 0.5f) * (PI_F / 8.0f));
    const float shfa_l = 0.9f + 0.65f * (float)yy;

    auto pair_term = [&](int j, int k2) -> float {
        float4 u1 = u4_s[m][j], u2 = u4_s[m][k2];
        float ca = u1.x * u2.x + u1.y * u2.y + u1.z * u2.z;   // = 0.95*cos
        float sa = sqrtf(1.0f - ca * ca);                     // ca^2 <= 0.9025, safe
        float dd = (u1.w + u2.w) - shfa_l;                    // (d1+d2)/2 - shfa
        float f2 = exp2f(dd * dd * K_A2);
        float x  = 0.5f + ca * cz2 + sa * sz2;
        float x2 = x * x, x4 = x2 * x2, x8 = x4 * x4, x16 = x8 * x8;
        float tc = fca_s[m][j] * fca_s[m][k2];                // = 2*fc1*fc2
        return (x16 * x16) * (f2 * tc);
    };

    #pragma unroll
    for (int spa = 0; spa < 4; ++spa) {
        #pragma unroll
        for (int spb = spa; spb < 4; ++spb) {
            const int pidx = spa * (9 - spa) / 2 + (spb - spa);
            const int na  = nsp_s[m][spa];
            const int nb2 = nsp_s[m][spb];
            float acc = 0.0f;
            if (spa == spb) {
                // triangular pair stream (jj<kk), stride 2 starting at parity
                int jj = 0, kk = 1 + par;
                while (jj < na - 1 && kk >= na) { int ov = kk - na; ++jj; kk = jj + 1 + ov; }
                while (jj < na - 1) {
                    acc += pair_term(bidx_s[m][spa][jj], bidx_s[m][spa][kk]);
                    kk += 2;
                    while (jj < na - 1 && kk >= na) { int ov = kk - na; ++jj; kk = jj + 1 + ov; }
                }
            } else {
                // rectangular pair stream
                int jj = 0, kk = par;
                while (jj < na && kk >= nb2) { kk -= nb2; ++jj; }
                while (jj < na) {
                    acc += pair_term(bidx_s[m][spa][jj], bidx_s[m][spb][kk]);
                    kk += 2;
                    while (jj < na && kk >= nb2) { kk -= nb2; ++jj; }
                }
            }
            float other = __shfl(acc, lane32 + 32);           // add the other half's partial
            if (lane < 32) aev[64 + pidx * 32 + lane32] = acc + other;
        }
    }
}

// ---------------- kernel B: MLP, 8 atoms of one species (global tile) per block ----------------
// Weight loads explicitly software-pipelined: group f+4's weights issue BEFORE group f's FMAs
// (double-buffered wa/wb register sets) so ~200cy L2 latency hides under the FMA stream.
__global__ __launch_bounds__(256) void mlp_kernel(const float* __restrict__ aev_ws,
                                                  const int* __restrict__ mol_cnt,
                                                  const int* __restrict__ mol_lst,
                                                  const float* __restrict__ W1, const float* __restrict__ b1,
                                                  const float* __restrict__ W2, const float* __restrict__ b2,
                                                  const float* __restrict__ W3, const float* __restrict__ b3,
                                                  const float* __restrict__ W4, const float* __restrict__ b4,
                                                  float* __restrict__ out) {
    const int blk   = blockIdx.x;
    const int s     = blk & 3;
    const int tile0 = blk >> 2;
    const int t     = threadIdx.x;
    const int lane  = t & 63;

    // ---- 64-lane prefix scan over per-molecule species counts ----
    const int c0 = lane * 2, c1 = c0 + 1;
    const int n0 = mol_cnt[c0 * S_ + s];
    const int n1 = mol_cnt[c1 * S_ + s];
    const int pairc = n0 + n1;
    int scan = pairc;                     // inclusive scan over lane pairs
    #pragma unroll
    for (int off = 1; off < 64; off <<= 1) {
        int v = __shfl_up(scan, off);
        if (lane >= off) scan += v;
    }
    const int cntS = __shfl(scan, 63);

    __shared__ __attribute__((aligned(16))) float aev_s[8][FAEV];  // overlays h2(8x128)+h3(8x96)
    __shared__ __attribute__((aligned(16))) float h1_s[8][160];
    float (*h2_s)[128] = (float(*)[128])&aev_s[0][0];
    float (*h3_s)[96]  = (float(*)[96])(&aev_s[0][0] + 8 * 128);

    const float* W1s = W1 + s * (FAEV * 160);
    const float* b1s = b1 + s * 160;
    const float* W2s = W2 + s * (160 * 128);
    const float* b2s = b2 + s * 128;
    const float* W3s = W3 + s * (128 * 96);
    const float* b3s = b3 + s * 96;
    const float* W4s = W4 + s * 96;
    const float  bb4 = b4[s];

    for (int tile = tile0; tile * 8 < cntS; tile += MLP_TILES) {
        const int base = tile * 8;

        // ---- resolve the 8 global-list slots to absolute atom ids (all waves, no LDS) ----
        int myAtom = -1;                  // absolute atom id for this thread's row m = t>>5
        #pragma unroll
        for (int m = 0; m < 8; ++m) {
            int g = base + m;
            int atomAbs = -1;
            if (g < cntS) {
                unsigned long long mask = __ballot(scan > g);
                int L = (int)__builtin_ctzll(mask);
                int exclL = __shfl(scan, L) - __shfl(pairc, L);
                int n0L   = __shfl(n0, L);
                int loc = g - exclL;
                int cL  = 2 * L;
                if (loc >= n0L) { cL += 1; loc -= n0L; }
                atomAbs = cL * A_ + mol_lst[(cL * S_ + s) * A_ + loc];
            }
            if ((t >> 5) == m) myAtom = atomAbs;
        }

        // ---- load 8 AEV rows (32 lanes per row, 3 float4 each) ----
        {
            int mrow = t >> 5, l = t & 31;
            float4* dst = (float4*)&aev_s[mrow][0];
            if (myAtom >= 0) {
                const float4* src = (const float4*)(aev_ws + (size_t)myAtom * FAEV);
                dst[l]      = src[l];
                dst[l + 32] = src[l + 32];
                dst[l + 64] = src[l + 64];
            } else {
                dst[l]      = make_float4(0.f, 0.f, 0.f, 0.f);
                dst[l + 32] = make_float4(0.f, 0.f, 0.f, 0.f);
                dst[l + 64] = make_float4(0.f, 0.f, 0.f, 0.f);
            }
        }
        __syncthreads();

        // ---- layer 1: 384 -> 160, 2-stage weight prefetch ----
        if (t < 160) {
            const float* Wp = W1s + t;
            float acc[8];
            #pragma unroll
            for (int m = 0; m < 8; ++m) acc[m] = 0.0f;
            float wa[4], wb[4];
            #pragma unroll
            for (int j = 0; j < 4; ++j) wa[j] = Wp[j * 160];
            for (int f = 0; f < FAEV; f += 8) {
                const int fb = f + 4;
                #pragma unroll
                for (int j = 0; j < 4; ++j) wb[j] = Wp[(fb + j) * 160];
                #pragma unroll
                for (int m = 0; m < 8; ++m) {
                    float4 av = *(const float4*)&aev_s[m][f];
                    acc[m] += av.x * wa[0] + av.y * wa[1] + av.z * wa[2] + av.w * wa[3];
                }
                const int fa = (f + 8 < FAEV) ? f + 8 : 0;   // wrap: dead prefetch on last iter
                #pragma unroll
                for (int j = 0; j < 4; ++j) wa[j] = Wp[(fa + j) * 160];
                #pragma unroll
                for (int m = 0; m < 8; ++m) {
                    float4 av = *(const float4*)&aev_s[m][fb];
                    acc[m] += av.x * wb[0] + av.y * wb[1] + av.z * wb[2] + av.w * wb[3];
                }
            }
            float bb = b1s[t];
            #pragma unroll
            for (int m = 0; m < 8; ++m) {
                float x = acc[m] + bb;
                h1_s[m][t] = (x > 0.f) ? x : 0.1f * (__expf(10.f * x) - 1.f);
            }
        }
        __syncthreads();   // aev_s dead -> reuse as h2/h3

        // ---- layer 2: 160 -> 128, 2-stage weight prefetch ----
        if (t < 128) {
            const float* Wp = W2s + t;
            float acc[8];
            #pragma unroll
            for (int m = 0; m < 8; ++m) acc[m] = 0.0f;
            float wa[4], wb[4];
            #pragma unroll
            for (int j = 0; j < 4; ++j) wa[j] = Wp[j * 128];
            for (int f = 0; f < 160; f += 8) {
                const int fb = f + 4;
                #pragma unroll
                for (int j = 0; j < 4; ++j) wb[j] = Wp[(fb + j) * 128];
                #pragma unroll
                for (int m = 0; m < 8; ++m) {
                    float4 av = *(const float4*)&h1_s[m][f];
                    acc[m] += av.x * wa[0] + av.y * wa[1] + av.z * wa[2] + av.w * wa[3];
                }
                const int fa = (f + 8 < 160) ? f + 8 : 0;
                #pragma unroll
                for (int j = 0; j < 4; ++j) wa[j] = Wp[(fa + j) * 128];
                #pragma unroll
                for (int m = 0; m < 8; ++m) {
                    float4 av = *(const float4*)&h1_s[m][fb];
                    acc[m] += av.x * wb[0] + av.y * wb[1] + av.z * wb[2] + av.w * wb[3];
                }
            }
            float bb = b2s[t];
            #pragma unroll
            for (int m = 0; m < 8; ++m) {
                float x = acc[m] + bb;
                h2_s[m][t] = (x > 0.f) ? x : 0.1f * (__expf(10.f * x) - 1.f);
            }
        }
        __syncthreads();

        // ---- layer 3: 128 -> 96, 2-stage weight prefetch ----
        if (t < 96) {
            const float* Wp = W3s + t;
            float acc[8];
            #pragma unroll
            for (int m = 0; m < 8; ++m) acc[m] = 0.0f;
            float wa[4], wb[4];
            #pragma unroll
            for (int j = 0; j < 4; ++j) wa[j] = Wp[j * 96];
            for (int f = 0; f < 128; f += 8) {
                const int fb = f + 4;
                #pragma unroll
                for (int j = 0; j < 4; ++j) wb[j] = Wp[(fb + j) * 96];
                #pragma unroll
                for (int m = 0; m < 8; ++m) {
                    float4 av = *(const float4*)&h2_s[m][f];
                    acc[m] += av.x * wa[0] + av.y * wa[1] + av.z * wa[2] + av.w * wa[3];
                }
                const int fa = (f + 8 < 128) ? f + 8 : 0;
                #pragma unroll
                for (int j = 0; j < 4; ++j) wa[j] = Wp[(fa + j) * 96];
                #pragma unroll
                for (int m = 0; m < 8; ++m) {
                    float4 av = *(const float4*)&h2_s[m][fb];
                    acc[m] += av.x * wb[0] + av.y * wb[1] + av.z * wb[2] + av.w * wb[3];
                }
            }
            float bb = b3s[t];
            #pragma unroll
            for (int m = 0; m < 8; ++m) {
                float x = acc[m] + bb;
                h3_s[m][t] = (x > 0.f) ? x : 0.1f * (__expf(10.f * x) - 1.f);
            }
        }
        __syncthreads();

        // ---- layer 4: 96 -> 1, all 8 rows in parallel (32 lanes each) ----
        {
            int m = t >> 5, l = t & 31;
            if (myAtom >= 0) {
                float p = h3_s[m][l]      * W4s[l]
                        + h3_s[m][l + 32] * W4s[l + 32]
                        + h3_s[m][l + 64] * W4s[l + 64];
                #pragma unroll
                for (int off = 16; off >= 1; off >>= 1)
                    p += __shfl_xor(p, off, 32);
                if (l == 0) atomicAdd(&out[myAtom >> 6], p + bb4);
            }
        }
        __syncthreads();   // protect LDS before next tile (rare stride iteration)
    }
}

extern "C" void kernel_launch(void* const* d_in, const int* in_sizes, int n_in,
                              void* d_out, int out_size, void* d_ws, size_t ws_size,
                              hipStream_t stream) {
    const int*   element_idxs  = (const int*)d_in[0];
    const int*   neighbor_idxs = (const int*)d_in[1];
    const float* distances     = (const float*)d_in[2];
    const float* diff_vectors  = (const float*)d_in[3];
    const float* W1 = (const float*)d_in[4];
    const float* b1 = (const float*)d_in[5];
    const float* W2 = (const float*)d_in[6];
    const float* b2 = (const float*)d_in[7];
    const float* W3 = (const float*)d_in[8];
    const float* b3 = (const float*)d_in[9];
    const float* W4 = (const float*)d_in[10];
    const float* b4 = (const float*)d_in[11];
    float* out = (float*)d_out;

    // workspace layout
    float* aev_ws  = (float*)d_ws;                                       // 8192*384 f32 = 12.58 MB
    int*   mol_cnt = (int*)((char*)d_ws + (size_t)NATOM * FAEV * 4);     // 512 ints
    int*   mol_lst = mol_cnt + C_ * S_;                                  // 512*64 ints

    hipLaunchKernelGGL(aev_kernel, dim3(NATOM / 4), dim3(256), 0, stream,
                       element_idxs, neighbor_idxs, distances, diff_vectors,
                       aev_ws, mol_cnt, mol_lst, out);
    hipLaunchKernelGGL(mlp_kernel, dim3(S_ * MLP_TILES), dim3(256), 0, stream,
                       aev_ws, mol_cnt, mol_lst,
                       W1, b1, W2, b2, W3, b3, W4, b4, out);
}